// Round 11
// baseline (385.747 us; speedup 1.0000x reference)
//
#include <hip/hip_runtime.h>
#include <math.h>

#define NN 16384
#define QPW 2     // queries per wave
#define CAP 128   // per-query LDS candidate buffer (u64 keys)
#define WM 64     // shrink watermark; shrink inside push keeps cnt <= 127
#define KTOP 17   // keep top-17 (incl. self at dist~0), drop self at merge

typedef unsigned long long u64;

// ---------------- pack coords: x[:, :3] -> float4(x,y,z,|p|^2) ----------------
__global__ __launch_bounds__(256) void pack_coords(const float* __restrict__ x,
                                                   float4* __restrict__ coo) {
  int i = blockIdx.x * 256 + threadIdx.x;
  float a = x[i * 64 + 0];
  float b = x[i * 64 + 1];
  float c = x[i * 64 + 2];
  coo[i] = make_float4(a, b, c, a * a + b * b + c * c);
}

__device__ __forceinline__ int mbcnt64(u64 mask) {
  return __builtin_amdgcn_mbcnt_hi(
      (unsigned)(mask >> 32),
      __builtin_amdgcn_mbcnt_lo((unsigned)mask, 0));
}

// monotone float -> uint mapping (preserves total order incl. negatives)
__device__ __forceinline__ unsigned fmap(float d) {
  unsigned ub = __float_as_uint(d);
  return ub ^ ((unsigned)((int)ub >> 31) | 0x80000000u);
}

__device__ __forceinline__ float unfmap(unsigned ub) {
  unsigned fb = (ub & 0x80000000u) ? (ub ^ 0x80000000u) : ~ub;
  return __uint_as_float(fb);
}

// fp32 <-> bf16 (RNE, NaN-free data)
__device__ __forceinline__ unsigned short f2bf(float f) {
  unsigned u = __float_as_uint(f);
  return (unsigned short)((u + 0x7FFFu + ((u >> 16) & 1u)) >> 16);
}
__device__ __forceinline__ float bf2f(unsigned short h) {
  return __uint_as_float(((unsigned)h) << 16);
}

__device__ __forceinline__ u64 u64min(u64 a, u64 b) { return a < b ? a : b; }
__device__ __forceinline__ u64 u64max(u64 a, u64 b) { return a > b ? a : b; }

// full bitonic sort of 128 u64 keys held as 2 regs/lane, virtual index
// i0 = lane (r0), i1 = lane+64 (r1). Ascending.
__device__ __forceinline__ void sort128(u64& r0, u64& r1, int lane) {
#pragma unroll
  for (int k = 2; k <= 128; k <<= 1) {
    if (k == 128) {  // jj = 64 stage: partner is the other reg, same lane
      u64 lo = u64min(r0, r1);
      r1 = u64max(r0, r1);
      r0 = lo;
    }
#pragma unroll
    for (int jj = (k == 128 ? 32 : (k >> 1)); jj >= 1; jj >>= 1) {
      const bool up = (lane & jj) == 0;
      const bool asc0 = (lane & k) == 0;
      const bool asc1 = ((lane | 64) & k) == 0;
      u64 o0 = __shfl_xor(r0, jj);
      u64 o1 = __shfl_xor(r1, jj);
      r0 = (up == asc0) ? u64min(r0, o0) : u64max(r0, o0);
      r1 = (up == asc1) ? u64min(r1, o1) : u64max(r1, o1);
    }
  }
}

// radix-select shrink: find p = KTOP-th smallest mapped distance among
// buf[0..cnt), keep all entries with d <= p (ties kept -> exactness),
// compact to front, tighten th. No cross-lane shuffles; scalar-pipe heavy.
__device__ __forceinline__ void radix_shrink(u64* buf, int& cnt, float& th,
                                             int lane) {
  const u64 k0 = (lane < cnt) ? buf[lane] : ~0ull;
  const u64 k1 = (lane + 64 < cnt) ? buf[lane + 64] : ~0ull;
  const unsigned d0 = (unsigned)(k0 >> 32);
  const unsigned d1 = (unsigned)(k1 >> 32);
  unsigned p = 0u;
#pragma unroll
  for (int b = 31; b >= 0; --b) {
    const unsigned c = p | (1u << b);
    const u64 b0 = __ballot(d0 < c);
    const u64 b1 = __ballot(d1 < c);
    const int n = __popcll(b0) + __popcll(b1);
    if (n < KTOP) p = c;  // invariant: count(d < p) < KTOP
  }
  const bool v0 = d0 <= p;
  const bool v1 = d1 <= p;
  const u64 m0 = __ballot(v0);
  const u64 m1 = __ballot(v1);
  const int base = __popcll(m0);
  if (v0) buf[mbcnt64(m0)] = k0;
  if (v1) buf[base + mbcnt64(m1)] = k1;
  cnt = base + __popcll(m1);
  th = unfmap(p);
}

// ---------------- kNN phase A: wave handles 2 nodes over HALF the database.
// Grid = 4096 blocks (16/CU) for real occupancy slack. Per (node,half):
// exact top-17 of that half, written as sorted u64 keys to part[node][half].
// Named prefetch slots only (r9 lesson: arrays demote to LDS/scratch).
__global__ __launch_bounds__(256) void knn_part(const float4* __restrict__ coo,
                                                u64* __restrict__ part) {
  __shared__ u64 bufs[4][QPW][CAP];  // 8 KB
  const int lane = threadIdx.x & 63;
  const int wid = threadIdx.x >> 6;
  const int half = blockIdx.x & 1;
  const int node0 = (blockIdx.x >> 1) * (4 * QPW) + wid * QPW;
  const int cb = half * 128;  // candidate step base (64-wide steps)

  float nx[QPW], ny[QPW], nz[QPW], sq[QPW], th[QPW];
  int cnt[QPW];
#pragma unroll
  for (int q = 0; q < QPW; ++q) {
    const float4 me = coo[node0 + q];
    nx[q] = -2.0f * me.x;
    ny[q] = -2.0f * me.y;
    nz[q] = -2.0f * me.z;
    sq[q] = me.w;
    cnt[q] = 0;
  }

  // pre-fill: first 128 candidates of this half -> tight threshold at once
  {
    const float4 pa = coo[cb * 64 + lane];
    const float4 pb = coo[cb * 64 + 64 + lane];
#pragma unroll
    for (int q = 0; q < QPW; ++q) {
      const float d0 = sq[q] + fmaf(nx[q], pa.x,
                           fmaf(ny[q], pa.y, fmaf(nz[q], pa.z, pa.w)));
      const float d1 = sq[q] + fmaf(nx[q], pb.x,
                           fmaf(ny[q], pb.y, fmaf(nz[q], pb.z, pb.w)));
      bufs[wid][q][lane] = ((u64)fmap(d0) << 32) | (unsigned)(cb * 64 + lane);
      bufs[wid][q][64 + lane] =
          ((u64)fmap(d1) << 32) | (unsigned)(cb * 64 + 64 + lane);
      cnt[q] = 128;
      radix_shrink(bufs[wid][q], cnt[q], th[q], lane);
    }
  }

  // named prefetch slots: relative steps 2,3,4,5
  float4 s0 = coo[(cb + 2) * 64 + lane];
  float4 s1 = coo[(cb + 3) * 64 + lane];
  float4 s2 = coo[(cb + 4) * 64 + lane];
  float4 s3 = coo[(cb + 5) * 64 + lane];

  auto body = [&](const float4 cur, const int rel) {
    const int j = (cb + rel) * 64 + lane;
    float dd[QPW];
#pragma unroll
    for (int q = 0; q < QPW; ++q)
      dd[q] = sq[q] + fmaf(nx[q], cur.x,
                           fmaf(ny[q], cur.y, fmaf(nz[q], cur.z, cur.w)));
    u64 mk[QPW];
#pragma unroll
    for (int q = 0; q < QPW; ++q) mk[q] = __ballot(dd[q] <= th[q]);
    if (mk[0] | mk[1]) {
#pragma unroll
      for (int q = 0; q < QPW; ++q) {
        if (mk[q]) {  // wave-uniform
          if (dd[q] <= th[q])
            bufs[wid][q][cnt[q] + mbcnt64(mk[q])] =
                ((u64)fmap(dd[q]) << 32) | (unsigned)j;
          cnt[q] += __popcll(mk[q]);
          if (cnt[q] >= WM) radix_shrink(bufs[wid][q], cnt[q], th[q], lane);
        }
      }
    }
  };

  // relative steps 2..125 in 31 groups of 4; epilogue 126,127.
  // Over-reads (rel 128,129 at g=30, half=1) land in the 256 KB pad after coo.
#pragma unroll 1
  for (int g = 0; g < 31; ++g) {
    const int base = 2 + g * 4;
    body(s0, base + 0);
    s0 = coo[(cb + base + 4) * 64 + lane];
    body(s1, base + 1);
    s1 = coo[(cb + base + 5) * 64 + lane];
    body(s2, base + 2);
    s2 = coo[(cb + base + 6) * 64 + lane];
    body(s3, base + 3);
    s3 = coo[(cb + base + 7) * 64 + lane];
  }
  body(s0, 126);
  body(s1, 127);

#pragma unroll 1
  for (int q = 0; q < QPW; ++q) {
    u64 r0 = (lane < cnt[q]) ? bufs[wid][q][lane] : ~0ull;
    u64 r1 = (lane + 64 < cnt[q]) ? bufs[wid][q][lane + 64] : ~0ull;
    sort128(r0, r1, lane);
    if (lane < KTOP) part[(node0 + q) * 34 + half * 17 + lane] = r0;
  }
}

// ---------------- kNN phase B: merge 2 sorted 17-lists -> exact top-16 ------
__global__ __launch_bounds__(256) void knn_merge(const u64* __restrict__ part,
                                                 int* __restrict__ src) {
  const int lane = threadIdx.x & 63;
  const int wid = threadIdx.x >> 6;
  const int node = blockIdx.x * 4 + wid;
  u64 r0 = (lane < 34) ? part[node * 34 + lane] : ~0ull;
  u64 r1 = ~0ull;
  sort128(r0, r1, lane);
  const int idx = (int)(r0 & 0xFFFFFFFFull);
  const u64 selfm = __ballot((lane < KTOP) && (idx == node));
  const int s = selfm ? (__ffsll((long long)selfm) - 1) : 99;
  const int outrank = lane - (lane > s ? 1 : 0);
  if (lane < KTOP && lane != s && outrank < 16) src[node * 16 + outrank] = idx;
}

// ---------------- fused q|k|v|s GEMM: [N,KD] x 4x[KD,128] ----------
// q,s -> fp32 qs[node][256] (q: 0..127, s: 128..255)
// k,v -> bf16 kvh[node][256] (k: 0..127, v: 128..255) -- halves attn gathers
template <int KD>
__global__ __launch_bounds__(256) void gemm_qkvs(
    const float* __restrict__ X, const float* __restrict__ W0,
    const float* __restrict__ W1, const float* __restrict__ W2,
    const float* __restrict__ W3, const float* __restrict__ B0,
    const float* __restrict__ B1, const float* __restrict__ B2,
    const float* __restrict__ B3, float* __restrict__ qs,
    unsigned short* __restrict__ kvh) {
  __shared__ float As[64][68];  // [k][row], padded k-stride 68
  __shared__ float Bs[64][64];  // [k][col]
  const int brow = blockIdx.x * 64;
  const int by = blockIdx.y;          // 0..7 -> (matrix, half)
  const int wi = by >> 1;
  const float* W = wi == 0 ? W0 : wi == 1 ? W1 : wi == 2 ? W2 : W3;
  const float* bias = wi == 0 ? B0 : wi == 1 ? B1 : wi == 2 ? B2 : B3;
  const int cbase = (by & 1) * 64;
  const int tx = threadIdx.x & 15;   // col group (4 cols)
  const int ty = threadIdx.x >> 4;   // row group (4 rows)

  float acc[4][4] = {};
  for (int k0 = 0; k0 < KD; k0 += 64) {
    __syncthreads();
#pragma unroll
    for (int i = 0; i < 4; ++i) {  // stage A transposed: 64 rows x 64 k
      const int flat = threadIdx.x * 4 + i * 1024;
      const int r = flat >> 6, kk = flat & 63;
      const float4 v = *(const float4*)&X[(brow + r) * KD + k0 + kk];
      As[kk + 0][r] = v.x;
      As[kk + 1][r] = v.y;
      As[kk + 2][r] = v.z;
      As[kk + 3][r] = v.w;
    }
#pragma unroll
    for (int i = 0; i < 4; ++i) {  // stage B: 64 k x 64 cols
      const int flat = threadIdx.x * 4 + i * 1024;
      const int kk = flat >> 6, c = flat & 63;
      *(float4*)&Bs[kk][c] = *(const float4*)&W[(k0 + kk) * 128 + cbase + c];
    }
    __syncthreads();
#pragma unroll 8
    for (int k = 0; k < 64; ++k) {
      const float4 a = *(const float4*)&As[k][ty * 4];
      const float4 b = *(const float4*)&Bs[k][tx * 4];
      const float av[4] = {a.x, a.y, a.z, a.w};
      const float bv[4] = {b.x, b.y, b.z, b.w};
#pragma unroll
      for (int i = 0; i < 4; ++i)
#pragma unroll
        for (int jj = 0; jj < 4; ++jj)
          acc[i][jj] = fmaf(av[i], bv[jj], acc[i][jj]);
    }
  }
  const float4 bi = *(const float4*)&bias[cbase + tx * 4];
  const int col = cbase + tx * 4;
#pragma unroll
  for (int i = 0; i < 4; ++i) {
    const int row = brow + ty * 4 + i;
    float4 o;
    o.x = acc[i][0] + bi.x;
    o.y = acc[i][1] + bi.y;
    o.z = acc[i][2] + bi.z;
    o.w = acc[i][3] + bi.w;
    if (wi == 0) {
      *(float4*)&qs[row * 256 + col] = o;
    } else if (wi == 3) {
      *(float4*)&qs[row * 256 + 128 + col] = o;
    } else {
      ushort4 h;
      h.x = f2bf(o.x);
      h.y = f2bf(o.y);
      h.z = f2bf(o.z);
      h.w = f2bf(o.w);
      *(ushort4*)&kvh[row * 256 + (wi == 1 ? col : 128 + col)] = h;
    }
  }
}

// ---------------- attention, c=128: 32-lane group per node ----
// q,s fp32 from qs; K,V gathered as bf16 ushort4 (half the bytes of fp32).
__global__ __launch_bounds__(256) void attn_c128(
    const float* __restrict__ qs, const unsigned short* __restrict__ kvh,
    const int* __restrict__ src, const float* __restrict__ res,
    float* __restrict__ hout, int do_res) {
  const int g = threadIdx.x >> 5;  // 8 groups of 32 lanes per block
  const int node = blockIdx.x * 8 + g;
  const int c = threadIdx.x & 31;
  const float4 q4 = ((const float4*)(qs + node * 256))[c];

  int nb[16];
#pragma unroll
  for (int r = 0; r < 16; ++r) nb[r] = src[node * 16 + r];

  float p[16];
#pragma unroll
  for (int r = 0; r < 16; ++r) {
    const ushort4 k4 = ((const ushort4*)(kvh + nb[r] * 256))[c];
    p[r] = q4.x * bf2f(k4.x) + q4.y * bf2f(k4.y) + q4.z * bf2f(k4.z) +
           q4.w * bf2f(k4.w);
  }
#pragma unroll
  for (int o = 16; o; o >>= 1) {  // group-local (xor offsets < 32)
#pragma unroll
    for (int r = 0; r < 16; ++r) p[r] += __shfl_xor(p[r], o);
  }

  float m = p[0];
#pragma unroll
  for (int r = 1; r < 16; ++r) m = fmaxf(m, p[r]);
  float w[16];
  float den = 0.0f;
#pragma unroll
  for (int r = 0; r < 16; ++r) {
    w[r] = __expf((p[r] - m) * 0.088388347648318447f);  // 1/sqrt(128)
    den += w[r];
  }
  const float inv = 1.0f / den;
  float o0 = 0.0f, o1 = 0.0f, o2 = 0.0f, o3 = 0.0f;
#pragma unroll
  for (int r = 0; r < 16; ++r) {
    const ushort4 v4 = ((const ushort4*)(kvh + nb[r] * 256 + 128))[c];
    const float ww = w[r] * inv;
    o0 = fmaf(ww, bf2f(v4.x), o0);
    o1 = fmaf(ww, bf2f(v4.y), o1);
    o2 = fmaf(ww, bf2f(v4.z), o2);
    o3 = fmaf(ww, bf2f(v4.w), o3);
  }
  const float4 s4 = ((const float4*)(qs + node * 256 + 128))[c];
  float r0 = o0 + s4.x, r1 = o1 + s4.y, r2 = o2 + s4.z, r3 = o3 + s4.w;
  if (do_res) {
    const float4 h4 = ((const float4*)(res + node * 128))[c];
    r0 += h4.x;
    r1 += h4.y;
    r2 += h4.z;
    r3 += h4.w;
  }
  ((float4*)(hout + node * 128))[c] =
      make_float4(tanhf(r0), tanhf(r1), tanhf(r2), tanhf(r3));
}

// ---------------- layer 3 GEMM: [N,128] x 4x[128,3] -> [N,12] ----------------
__global__ __launch_bounds__(256) void gemm_qkvs3(
    const float* __restrict__ H, const float* __restrict__ W0,
    const float* __restrict__ W1, const float* __restrict__ W2,
    const float* __restrict__ W3, const float* __restrict__ B0,
    const float* __restrict__ B1, const float* __restrict__ B2,
    const float* __restrict__ B3, float* __restrict__ out) {
  __shared__ float hs[64][132];
  __shared__ float wsh[128 * 12];
  __shared__ float bsh[12];
  const int brow = blockIdx.x * 64;
  if (threadIdx.x < 12) {
    const int mi = threadIdx.x / 3, c = threadIdx.x % 3;
    const float* Bsel = mi == 0 ? B0 : mi == 1 ? B1 : mi == 2 ? B2 : B3;
    bsh[threadIdx.x] = Bsel[c];
  }
  for (int t = threadIdx.x; t < 1536; t += 256) {
    const int k = t / 12, cc = t % 12;
    const int mi = cc / 3, c = cc % 3;
    const float* Wsel = mi == 0 ? W0 : mi == 1 ? W1 : mi == 2 ? W2 : W3;
    wsh[t] = Wsel[k * 3 + c];
  }
#pragma unroll
  for (int i = 0; i < 8; ++i) {
    const int flat = threadIdx.x * 4 + i * 1024;
    const int r = flat >> 7, kk = flat & 127;
    *(float4*)&hs[r][kk] = *(const float4*)&H[(brow + r) * 128 + kk];
  }
  __syncthreads();
  const int r = threadIdx.x >> 2;
  const int part = threadIdx.x & 3;
  float a0 = 0.0f, a1 = 0.0f, a2 = 0.0f;
#pragma unroll 4
  for (int k = 0; k < 128; ++k) {
    const float h = hs[r][k];
    a0 = fmaf(h, wsh[k * 12 + part * 3 + 0], a0);
    a1 = fmaf(h, wsh[k * 12 + part * 3 + 1], a1);
    a2 = fmaf(h, wsh[k * 12 + part * 3 + 2], a2);
  }
  const int row = brow + r;
  out[row * 12 + part * 3 + 0] = a0 + bsh[part * 3 + 0];
  out[row * 12 + part * 3 + 1] = a1 + bsh[part * 3 + 1];
  out[row * 12 + part * 3 + 2] = a2 + bsh[part * 3 + 2];
}

// ---------------- attention, c=3: 16 lanes per node ----------------
__global__ __launch_bounds__(256) void attn_c3(const float* __restrict__ q3,
                                               const int* __restrict__ src,
                                               float* __restrict__ out) {
  const int gid = blockIdx.x * 256 + threadIdx.x;
  const int node = gid >> 4, r = gid & 15;
  const int j = src[node * 16 + r];
  const float* qn = q3 + node * 12;
  const float* kj = q3 + j * 12 + 3;
  float alpha = (qn[0] * kj[0] + qn[1] * kj[1] + qn[2] * kj[2]) *
                0.57735026918962576f;  // 1/sqrt(3)
  float m = alpha;
#pragma unroll
  for (int o = 8; o; o >>= 1) m = fmaxf(m, __shfl_xor(m, o, 16));
  const float e = __expf(alpha - m);
  float den = e;
#pragma unroll
  for (int o = 8; o; o >>= 1) den += __shfl_xor(den, o, 16);
  const float wgt = e / den;
  const float* vj = q3 + j * 12 + 6;
  float o0 = wgt * vj[0], o1 = wgt * vj[1], o2 = wgt * vj[2];
#pragma unroll
  for (int o = 8; o; o >>= 1) {
    o0 += __shfl_xor(o0, o, 16);
    o1 += __shfl_xor(o1, o, 16);
    o2 += __shfl_xor(o2, o, 16);
  }
  if (r == 0) {
    const float* sn = q3 + node * 12 + 9;
    out[node * 3 + 0] = o0 + sn[0];
    out[node * 3 + 1] = o1 + sn[1];
    out[node * 3 + 2] = o2 + sn[2];
  }
}

extern "C" void kernel_launch(void* const* d_in, const int* in_sizes, int n_in,
                              void* d_out, int out_size, void* d_ws,
                              size_t ws_size, hipStream_t stream) {
  const float* x = (const float*)d_in[1];
  const float* Wq1 = (const float*)d_in[2];
  const float* bq1 = (const float*)d_in[3];
  const float* Wk1 = (const float*)d_in[4];
  const float* bk1 = (const float*)d_in[5];
  const float* Wv1 = (const float*)d_in[6];
  const float* bv1 = (const float*)d_in[7];
  const float* Ws1 = (const float*)d_in[8];
  const float* bs1 = (const float*)d_in[9];
  const float* Wq2 = (const float*)d_in[10];
  const float* bq2 = (const float*)d_in[11];
  const float* Wk2 = (const float*)d_in[12];
  const float* bk2 = (const float*)d_in[13];
  const float* Wv2 = (const float*)d_in[14];
  const float* bv2 = (const float*)d_in[15];
  const float* Ws2 = (const float*)d_in[16];
  const float* bs2 = (const float*)d_in[17];
  const float* Wq3 = (const float*)d_in[18];
  const float* bq3 = (const float*)d_in[19];
  const float* Wk3 = (const float*)d_in[20];
  const float* bk3 = (const float*)d_in[21];
  const float* Wv3 = (const float*)d_in[22];
  const float* bv3 = (const float*)d_in[23];
  const float* Ws3 = (const float*)d_in[24];
  const float* bs3 = (const float*)d_in[25];

  const size_t MB = 1024 * 1024;
  char* ws = (char*)d_ws;
  float* qs = (float*)(ws);                          // 16 MB (q|s fp32)
  u64* part = (u64*)(ws);                            // 4.5 MB, overlays qs:
                                                     // consumed by knn_merge
                                                     // before gemm writes qs
  unsigned short* kvh = (unsigned short*)(ws + 16 * MB);  // 8 MB (k|v bf16)
  float* h1 = (float*)(ws + 24 * MB);                // 8 MB
  float* h2 = (float*)(ws + 32 * MB);                // 8 MB
  int* src = (int*)(ws + 40 * MB);                   // 1 MB
  float4* coo = (float4*)(ws + 41 * MB);             // 256 KB + 256 KB pad
  float* q3 = (float*)(ws + 42 * MB);                // 768 KB
  float* out = (float*)d_out;

  pack_coords<<<NN / 256, 256, 0, stream>>>(x, coo);
  knn_part<<<NN / (4 * QPW) * 2, 256, 0, stream>>>(coo, part);
  knn_merge<<<NN / 4, 256, 0, stream>>>(part, src);
  gemm_qkvs<64><<<dim3(NN / 64, 8), 256, 0, stream>>>(
      x, Wq1, Wk1, Wv1, Ws1, bq1, bk1, bv1, bs1, qs, kvh);
  attn_c128<<<NN / 8, 256, 0, stream>>>(qs, kvh, src, nullptr, h1, 0);
  gemm_qkvs<128><<<dim3(NN / 64, 8), 256, 0, stream>>>(
      h1, Wq2, Wk2, Wv2, Ws2, bq2, bk2, bv2, bs2, qs, kvh);
  attn_c128<<<NN / 8, 256, 0, stream>>>(qs, kvh, src, h1, h2, 1);
  gemm_qkvs3<<<NN / 64, 256, 0, stream>>>(h2, Wq3, Wk3, Wv3, Ws3, bq3, bk3,
                                          bv3, bs3, q3);
  attn_c3<<<NN * 16 / 256, 256, 0, stream>>>(q3, src, out);
}

// Round 12
// 305.955 us; speedup vs baseline: 1.2608x; 1.2608x over previous
//
#include <hip/hip_runtime.h>
#include <math.h>

#define NN 16384
#define QPW 2     // queries per wave
#define CAP 128   // per-query LDS candidate buffer (u64 keys)
#define WM 64     // shrink watermark; shrink inside push keeps cnt <= 127
#define KTOP 17   // keep top-17 (incl. self at dist~0), drop self at output

typedef unsigned long long u64;

// ---------------- pack coords: x[:, :3] -> float4(x,y,z,|p|^2) ----------------
__global__ __launch_bounds__(256) void pack_coords(const float* __restrict__ x,
                                                   float4* __restrict__ coo) {
  int i = blockIdx.x * 256 + threadIdx.x;
  float a = x[i * 64 + 0];
  float b = x[i * 64 + 1];
  float c = x[i * 64 + 2];
  coo[i] = make_float4(a, b, c, a * a + b * b + c * c);
}

__device__ __forceinline__ int mbcnt64(u64 mask) {
  return __builtin_amdgcn_mbcnt_hi(
      (unsigned)(mask >> 32),
      __builtin_amdgcn_mbcnt_lo((unsigned)mask, 0));
}

// monotone float -> uint mapping (preserves total order incl. negatives)
__device__ __forceinline__ unsigned fmap(float d) {
  unsigned ub = __float_as_uint(d);
  return ub ^ ((unsigned)((int)ub >> 31) | 0x80000000u);
}

__device__ __forceinline__ float unfmap(unsigned ub) {
  unsigned fb = (ub & 0x80000000u) ? (ub ^ 0x80000000u) : ~ub;
  return __uint_as_float(fb);
}

// fp32 <-> bf16 (RNE, NaN-free data)
__device__ __forceinline__ unsigned short f2bf(float f) {
  unsigned u = __float_as_uint(f);
  return (unsigned short)((u + 0x7FFFu + ((u >> 16) & 1u)) >> 16);
}
__device__ __forceinline__ float bf2f(unsigned short h) {
  return __uint_as_float(((unsigned)h) << 16);
}

__device__ __forceinline__ u64 u64min(u64 a, u64 b) { return a < b ? a : b; }
__device__ __forceinline__ u64 u64max(u64 a, u64 b) { return a > b ? a : b; }

// full bitonic sort of 128 u64 keys held as 2 regs/lane, virtual index
// i0 = lane (r0), i1 = lane+64 (r1). Ascending. Used ONCE per query (final).
__device__ __forceinline__ void sort128(u64& r0, u64& r1, int lane) {
#pragma unroll
  for (int k = 2; k <= 128; k <<= 1) {
    if (k == 128) {  // jj = 64 stage: partner is the other reg, same lane
      u64 lo = u64min(r0, r1);
      r1 = u64max(r0, r1);
      r0 = lo;
    }
#pragma unroll
    for (int jj = (k == 128 ? 32 : (k >> 1)); jj >= 1; jj >>= 1) {
      const bool up = (lane & jj) == 0;
      const bool asc0 = (lane & k) == 0;
      const bool asc1 = ((lane | 64) & k) == 0;
      u64 o0 = __shfl_xor(r0, jj);
      u64 o1 = __shfl_xor(r1, jj);
      r0 = (up == asc0) ? u64min(r0, o0) : u64max(r0, o0);
      r1 = (up == asc1) ? u64min(r1, o1) : u64max(r1, o1);
    }
  }
}

// radix-select shrink: find p = KTOP-th smallest mapped distance among
// buf[0..cnt), keep all entries with d <= p (ties kept -> exactness),
// compact to front, tighten th. No cross-lane shuffles; scalar-pipe heavy.
__device__ __forceinline__ void radix_shrink(u64* buf, int& cnt, float& th,
                                             int lane) {
  const u64 k0 = (lane < cnt) ? buf[lane] : ~0ull;
  const u64 k1 = (lane + 64 < cnt) ? buf[lane + 64] : ~0ull;
  const unsigned d0 = (unsigned)(k0 >> 32);
  const unsigned d1 = (unsigned)(k1 >> 32);
  unsigned p = 0u;
#pragma unroll
  for (int b = 31; b >= 0; --b) {
    const unsigned c = p | (1u << b);
    const u64 b0 = __ballot(d0 < c);
    const u64 b1 = __ballot(d1 < c);
    const int n = __popcll(b0) + __popcll(b1);
    if (n < KTOP) p = c;  // invariant: count(d < p) < KTOP
  }
  const bool v0 = d0 <= p;
  const bool v1 = d1 <= p;
  const u64 m0 = __ballot(v0);
  const u64 m1 = __ballot(v1);
  const int base = __popcll(m0);
  if (v0) buf[mbcnt64(m0)] = k0;
  if (v1) buf[base + mbcnt64(m1)] = k1;
  cnt = base + __popcll(m1);
  th = unfmap(p);
}

// ---------------- kNN (r10 proven): wave handles 2 nodes over the FULL
// database. Pre-fill j=0..127 -> tight threshold immediately; main loop
// steps 2..255 at 64 cand/step with FOUR NAMED prefetch slots (r9 lesson:
// index-dependent arrays demote to LDS/scratch). Split-K (r11) regressed:
// per-half overhead duplication + looser per-half thresholds. -----------------
__global__ __launch_bounds__(256) void knn_kernel(const float4* __restrict__ coo,
                                                  int* __restrict__ src) {
  __shared__ u64 bufs[4][QPW][CAP];  // 8 KB
  const int lane = threadIdx.x & 63;
  const int wid = threadIdx.x >> 6;
  const int node0 = blockIdx.x * (4 * QPW) + wid * QPW;

  float nx[QPW], ny[QPW], nz[QPW], sq[QPW], th[QPW];
  int cnt[QPW];
#pragma unroll
  for (int q = 0; q < QPW; ++q) {
    const float4 me = coo[node0 + q];
    nx[q] = -2.0f * me.x;
    ny[q] = -2.0f * me.y;
    nz[q] = -2.0f * me.z;
    sq[q] = me.w;
    cnt[q] = 0;
  }

  // pre-fill: candidates j = 0..127 direct into buffer, shrink
  {
    const float4 pa = coo[lane];
    const float4 pb = coo[64 + lane];
#pragma unroll
    for (int q = 0; q < QPW; ++q) {
      const float d0 = sq[q] + fmaf(nx[q], pa.x,
                           fmaf(ny[q], pa.y, fmaf(nz[q], pa.z, pa.w)));
      const float d1 = sq[q] + fmaf(nx[q], pb.x,
                           fmaf(ny[q], pb.y, fmaf(nz[q], pb.z, pb.w)));
      bufs[wid][q][lane] = ((u64)fmap(d0) << 32) | (unsigned)lane;
      bufs[wid][q][64 + lane] = ((u64)fmap(d1) << 32) | (unsigned)(64 + lane);
      cnt[q] = 128;
      radix_shrink(bufs[wid][q], cnt[q], th[q], lane);
    }
  }

  // named prefetch slots: steps 2,3,4,5
  float4 s0 = coo[2 * 64 + lane];
  float4 s1 = coo[3 * 64 + lane];
  float4 s2 = coo[4 * 64 + lane];
  float4 s3 = coo[5 * 64 + lane];

  auto body = [&](const float4 cur, const int step) {
    const int j = step * 64 + lane;
    float dd[QPW];
#pragma unroll
    for (int q = 0; q < QPW; ++q)
      dd[q] = sq[q] + fmaf(nx[q], cur.x,
                           fmaf(ny[q], cur.y, fmaf(nz[q], cur.z, cur.w)));
    u64 mk[QPW];
#pragma unroll
    for (int q = 0; q < QPW; ++q) mk[q] = __ballot(dd[q] <= th[q]);
    if (mk[0] | mk[1]) {
#pragma unroll
      for (int q = 0; q < QPW; ++q) {
        if (mk[q]) {  // wave-uniform
          if (dd[q] <= th[q])
            bufs[wid][q][cnt[q] + mbcnt64(mk[q])] =
                ((u64)fmap(dd[q]) << 32) | (unsigned)j;
          cnt[q] += __popcll(mk[q]);
          if (cnt[q] >= WM) radix_shrink(bufs[wid][q], cnt[q], th[q], lane);
        }
      }
    }
  };

  // steps 2..253 in 63 groups of 4; slots referenced by NAME only.
  // Over-reads at g=62 (steps 256,257) stay inside the pad after coo.
#pragma unroll 1
  for (int g = 0; g < 63; ++g) {
    const int base = 2 + g * 4;
    body(s0, base + 0);
    s0 = coo[(base + 4) * 64 + lane];
    body(s1, base + 1);
    s1 = coo[(base + 5) * 64 + lane];
    body(s2, base + 2);
    s2 = coo[(base + 6) * 64 + lane];
    body(s3, base + 3);
    s3 = coo[(base + 7) * 64 + lane];
  }
  body(s0, 254);
  body(s1, 255);

#pragma unroll 1
  for (int q = 0; q < QPW; ++q) {
    // final: exact (d, idx)-sorted top-17 via one bitonic sort
    u64 r0 = (lane < cnt[q]) ? bufs[wid][q][lane] : ~0ull;
    u64 r1 = (lane + 64 < cnt[q]) ? bufs[wid][q][lane + 64] : ~0ull;
    sort128(r0, r1, lane);
    const int idx = (int)(r0 & 0xFFFFFFFFull);
    const u64 selfm = __ballot((lane < KTOP) && (idx == node0 + q));
    const int s = selfm ? (__ffsll((long long)selfm) - 1) : 99;
    const int outrank = lane - (lane > s ? 1 : 0);
    if (lane < KTOP && lane != s && outrank < 16)
      src[(node0 + q) * 16 + outrank] = idx;
  }
}

// ---------------- fused q|k|v|s GEMM: [N,KD] x 4x[KD,128] ----------
// q,s -> fp32 qs[node][256] (q: 0..127, s: 128..255)
// k,v -> bf16 kvh[node][256] (k: 0..127, v: 128..255) -- halves attn gathers
template <int KD>
__global__ __launch_bounds__(256) void gemm_qkvs(
    const float* __restrict__ X, const float* __restrict__ W0,
    const float* __restrict__ W1, const float* __restrict__ W2,
    const float* __restrict__ W3, const float* __restrict__ B0,
    const float* __restrict__ B1, const float* __restrict__ B2,
    const float* __restrict__ B3, float* __restrict__ qs,
    unsigned short* __restrict__ kvh) {
  __shared__ float As[64][68];  // [k][row], padded k-stride 68
  __shared__ float Bs[64][64];  // [k][col]
  const int brow = blockIdx.x * 64;
  const int by = blockIdx.y;          // 0..7 -> (matrix, half)
  const int wi = by >> 1;
  const float* W = wi == 0 ? W0 : wi == 1 ? W1 : wi == 2 ? W2 : W3;
  const float* bias = wi == 0 ? B0 : wi == 1 ? B1 : wi == 2 ? B2 : B3;
  const int cbase = (by & 1) * 64;
  const int tx = threadIdx.x & 15;   // col group (4 cols)
  const int ty = threadIdx.x >> 4;   // row group (4 rows)

  float acc[4][4] = {};
  for (int k0 = 0; k0 < KD; k0 += 64) {
    __syncthreads();
#pragma unroll
    for (int i = 0; i < 4; ++i) {  // stage A transposed: 64 rows x 64 k
      const int flat = threadIdx.x * 4 + i * 1024;
      const int r = flat >> 6, kk = flat & 63;
      const float4 v = *(const float4*)&X[(brow + r) * KD + k0 + kk];
      As[kk + 0][r] = v.x;
      As[kk + 1][r] = v.y;
      As[kk + 2][r] = v.z;
      As[kk + 3][r] = v.w;
    }
#pragma unroll
    for (int i = 0; i < 4; ++i) {  // stage B: 64 k x 64 cols
      const int flat = threadIdx.x * 4 + i * 1024;
      const int kk = flat >> 6, c = flat & 63;
      *(float4*)&Bs[kk][c] = *(const float4*)&W[(k0 + kk) * 128 + cbase + c];
    }
    __syncthreads();
#pragma unroll 8
    for (int k = 0; k < 64; ++k) {
      const float4 a = *(const float4*)&As[k][ty * 4];
      const float4 b = *(const float4*)&Bs[k][tx * 4];
      const float av[4] = {a.x, a.y, a.z, a.w};
      const float bv[4] = {b.x, b.y, b.z, b.w};
#pragma unroll
      for (int i = 0; i < 4; ++i)
#pragma unroll
        for (int jj = 0; jj < 4; ++jj)
          acc[i][jj] = fmaf(av[i], bv[jj], acc[i][jj]);
    }
  }
  const float4 bi = *(const float4*)&bias[cbase + tx * 4];
  const int col = cbase + tx * 4;
#pragma unroll
  for (int i = 0; i < 4; ++i) {
    const int row = brow + ty * 4 + i;
    float4 o;
    o.x = acc[i][0] + bi.x;
    o.y = acc[i][1] + bi.y;
    o.z = acc[i][2] + bi.z;
    o.w = acc[i][3] + bi.w;
    if (wi == 0) {
      *(float4*)&qs[row * 256 + col] = o;
    } else if (wi == 3) {
      *(float4*)&qs[row * 256 + 128 + col] = o;
    } else {
      ushort4 h;
      h.x = f2bf(o.x);
      h.y = f2bf(o.y);
      h.z = f2bf(o.z);
      h.w = f2bf(o.w);
      *(ushort4*)&kvh[row * 256 + (wi == 1 ? col : 128 + col)] = h;
    }
  }
}

// ---------------- attention, c=128: 32-lane group per node ----
// q,s fp32 from qs; K,V gathered as bf16 ushort4 (half the bytes of fp32).
__global__ __launch_bounds__(256) void attn_c128(
    const float* __restrict__ qs, const unsigned short* __restrict__ kvh,
    const int* __restrict__ src, const float* __restrict__ res,
    float* __restrict__ hout, int do_res) {
  const int g = threadIdx.x >> 5;  // 8 groups of 32 lanes per block
  const int node = blockIdx.x * 8 + g;
  const int c = threadIdx.x & 31;
  const float4 q4 = ((const float4*)(qs + node * 256))[c];

  int nb[16];
#pragma unroll
  for (int r = 0; r < 16; ++r) nb[r] = src[node * 16 + r];

  float p[16];
#pragma unroll
  for (int r = 0; r < 16; ++r) {
    const ushort4 k4 = ((const ushort4*)(kvh + nb[r] * 256))[c];
    p[r] = q4.x * bf2f(k4.x) + q4.y * bf2f(k4.y) + q4.z * bf2f(k4.z) +
           q4.w * bf2f(k4.w);
  }
#pragma unroll
  for (int o = 16; o; o >>= 1) {  // group-local (xor offsets < 32)
#pragma unroll
    for (int r = 0; r < 16; ++r) p[r] += __shfl_xor(p[r], o);
  }

  float m = p[0];
#pragma unroll
  for (int r = 1; r < 16; ++r) m = fmaxf(m, p[r]);
  float w[16];
  float den = 0.0f;
#pragma unroll
  for (int r = 0; r < 16; ++r) {
    w[r] = __expf((p[r] - m) * 0.088388347648318447f);  // 1/sqrt(128)
    den += w[r];
  }
  const float inv = 1.0f / den;
  float o0 = 0.0f, o1 = 0.0f, o2 = 0.0f, o3 = 0.0f;
#pragma unroll
  for (int r = 0; r < 16; ++r) {
    const ushort4 v4 = ((const ushort4*)(kvh + nb[r] * 256 + 128))[c];
    const float ww = w[r] * inv;
    o0 = fmaf(ww, bf2f(v4.x), o0);
    o1 = fmaf(ww, bf2f(v4.y), o1);
    o2 = fmaf(ww, bf2f(v4.z), o2);
    o3 = fmaf(ww, bf2f(v4.w), o3);
  }
  const float4 s4 = ((const float4*)(qs + node * 256 + 128))[c];
  float r0 = o0 + s4.x, r1 = o1 + s4.y, r2 = o2 + s4.z, r3 = o3 + s4.w;
  if (do_res) {
    const float4 h4 = ((const float4*)(res + node * 128))[c];
    r0 += h4.x;
    r1 += h4.y;
    r2 += h4.z;
    r3 += h4.w;
  }
  ((float4*)(hout + node * 128))[c] =
      make_float4(tanhf(r0), tanhf(r1), tanhf(r2), tanhf(r3));
}

// ---------------- layer 3 GEMM: [N,128] x 4x[128,3] -> [N,12] ----------------
__global__ __launch_bounds__(256) void gemm_qkvs3(
    const float* __restrict__ H, const float* __restrict__ W0,
    const float* __restrict__ W1, const float* __restrict__ W2,
    const float* __restrict__ W3, const float* __restrict__ B0,
    const float* __restrict__ B1, const float* __restrict__ B2,
    const float* __restrict__ B3, float* __restrict__ out) {
  __shared__ float hs[64][132];
  __shared__ float wsh[128 * 12];
  __shared__ float bsh[12];
  const int brow = blockIdx.x * 64;
  if (threadIdx.x < 12) {
    const int mi = threadIdx.x / 3, c = threadIdx.x % 3;
    const float* Bsel = mi == 0 ? B0 : mi == 1 ? B1 : mi == 2 ? B2 : B3;
    bsh[threadIdx.x] = Bsel[c];
  }
  for (int t = threadIdx.x; t < 1536; t += 256) {
    const int k = t / 12, cc = t % 12;
    const int mi = cc / 3, c = cc % 3;
    const float* Wsel = mi == 0 ? W0 : mi == 1 ? W1 : mi == 2 ? W2 : W3;
    wsh[t] = Wsel[k * 3 + c];
  }
#pragma unroll
  for (int i = 0; i < 8; ++i) {
    const int flat = threadIdx.x * 4 + i * 1024;
    const int r = flat >> 7, kk = flat & 127;
    *(float4*)&hs[r][kk] = *(const float4*)&H[(brow + r) * 128 + kk];
  }
  __syncthreads();
  const int r = threadIdx.x >> 2;
  const int part = threadIdx.x & 3;
  float a0 = 0.0f, a1 = 0.0f, a2 = 0.0f;
#pragma unroll 4
  for (int k = 0; k < 128; ++k) {
    const float h = hs[r][k];
    a0 = fmaf(h, wsh[k * 12 + part * 3 + 0], a0);
    a1 = fmaf(h, wsh[k * 12 + part * 3 + 1], a1);
    a2 = fmaf(h, wsh[k * 12 + part * 3 + 2], a2);
  }
  const int row = brow + r;
  out[row * 12 + part * 3 + 0] = a0 + bsh[part * 3 + 0];
  out[row * 12 + part * 3 + 1] = a1 + bsh[part * 3 + 1];
  out[row * 12 + part * 3 + 2] = a2 + bsh[part * 3 + 2];
}

// ---------------- attention, c=3: 16 lanes per node ----------------
__global__ __launch_bounds__(256) void attn_c3(const float* __restrict__ q3,
                                               const int* __restrict__ src,
                                               float* __restrict__ out) {
  const int gid = blockIdx.x * 256 + threadIdx.x;
  const int node = gid >> 4, r = gid & 15;
  const int j = src[node * 16 + r];
  const float* qn = q3 + node * 12;
  const float* kj = q3 + j * 12 + 3;
  float alpha = (qn[0] * kj[0] + qn[1] * kj[1] + qn[2] * kj[2]) *
                0.57735026918962576f;  // 1/sqrt(3)
  float m = alpha;
#pragma unroll
  for (int o = 8; o; o >>= 1) m = fmaxf(m, __shfl_xor(m, o, 16));
  const float e = __expf(alpha - m);
  float den = e;
#pragma unroll
  for (int o = 8; o; o >>= 1) den += __shfl_xor(den, o, 16);
  const float wgt = e / den;
  const float* vj = q3 + j * 12 + 6;
  float o0 = wgt * vj[0], o1 = wgt * vj[1], o2 = wgt * vj[2];
#pragma unroll
  for (int o = 8; o; o >>= 1) {
    o0 += __shfl_xor(o0, o, 16);
    o1 += __shfl_xor(o1, o, 16);
    o2 += __shfl_xor(o2, o, 16);
  }
  if (r == 0) {
    const float* sn = q3 + node * 12 + 9;
    out[node * 3 + 0] = o0 + sn[0];
    out[node * 3 + 1] = o1 + sn[1];
    out[node * 3 + 2] = o2 + sn[2];
  }
}

extern "C" void kernel_launch(void* const* d_in, const int* in_sizes, int n_in,
                              void* d_out, int out_size, void* d_ws,
                              size_t ws_size, hipStream_t stream) {
  const float* x = (const float*)d_in[1];
  const float* Wq1 = (const float*)d_in[2];
  const float* bq1 = (const float*)d_in[3];
  const float* Wk1 = (const float*)d_in[4];
  const float* bk1 = (const float*)d_in[5];
  const float* Wv1 = (const float*)d_in[6];
  const float* bv1 = (const float*)d_in[7];
  const float* Ws1 = (const float*)d_in[8];
  const float* bs1 = (const float*)d_in[9];
  const float* Wq2 = (const float*)d_in[10];
  const float* bq2 = (const float*)d_in[11];
  const float* Wk2 = (const float*)d_in[12];
  const float* bk2 = (const float*)d_in[13];
  const float* Wv2 = (const float*)d_in[14];
  const float* bv2 = (const float*)d_in[15];
  const float* Ws2 = (const float*)d_in[16];
  const float* bs2 = (const float*)d_in[17];
  const float* Wq3 = (const float*)d_in[18];
  const float* bq3 = (const float*)d_in[19];
  const float* Wk3 = (const float*)d_in[20];
  const float* bk3 = (const float*)d_in[21];
  const float* Wv3 = (const float*)d_in[22];
  const float* bv3 = (const float*)d_in[23];
  const float* Ws3 = (const float*)d_in[24];
  const float* bs3 = (const float*)d_in[25];

  const size_t MB = 1024 * 1024;
  char* ws = (char*)d_ws;
  float* qs = (float*)(ws);                               // 16 MB (q|s fp32)
  unsigned short* kvh = (unsigned short*)(ws + 16 * MB);  // 8 MB (k|v bf16)
  float* h1 = (float*)(ws + 24 * MB);                     // 8 MB
  float* h2 = (float*)(ws + 32 * MB);                     // 8 MB
  int* src = (int*)(ws + 40 * MB);                        // 1 MB
  float4* coo = (float4*)(ws + 41 * MB);                  // 256 KB + 256 KB pad
  float* q3 = (float*)(ws + 42 * MB);                     // 768 KB
  float* out = (float*)d_out;

  pack_coords<<<NN / 256, 256, 0, stream>>>(x, coo);
  knn_kernel<<<NN / (4 * QPW), 256, 0, stream>>>(coo, src);
  gemm_qkvs<64><<<dim3(NN / 64, 8), 256, 0, stream>>>(
      x, Wq1, Wk1, Wv1, Ws1, bq1, bk1, bv1, bs1, qs, kvh);
  attn_c128<<<NN / 8, 256, 0, stream>>>(qs, kvh, src, nullptr, h1, 0);
  gemm_qkvs<128><<<dim3(NN / 64, 8), 256, 0, stream>>>(
      h1, Wq2, Wk2, Wv2, Ws2, bq2, bk2, bv2, bs2, qs, kvh);
  attn_c128<<<NN / 8, 256, 0, stream>>>(qs, kvh, src, h1, h2, 1);
  gemm_qkvs3<<<NN / 64, 256, 0, stream>>>(h2, Wq3, Wk3, Wv3, Ws3, bq3, bk3,
                                          bv3, bs3, q3);
  attn_c3<<<NN * 16 / 256, 256, 0, stream>>>(q3, src, out);
}